// Round 10
// baseline (175.060 us; speedup 1.0000x reference)
//
#include <hip/hip_runtime.h>
#include <hip/hip_bf16.h>
#include <cstddef>

// Problem constants (reference: B=128, IN=1024, H=1024, TAU=1.0)
#define B_DIM  128
#define IN_DIM 1024
#define H_DIM  1024

constexpr float kDecay   = 1.0f - 0.01f;    // 1 - FAST_WEIGHT_DECAY
constexpr float kLrOverB = 0.01f / 128.0f;  // FAST_WEIGHT_LR / B

// ---------------------------------------------------------------------------
// global -> LDS direct DMA, 16 B per lane. Global address is PER-LANE (must
// include lane*16B); LDS dest is wave-uniform base + lane*16 (linear).
// ---------------------------------------------------------------------------
__device__ __forceinline__ void gload_lds16(const float* g, float* l)
{
    __builtin_amdgcn_global_load_lds(
        (const __attribute__((address_space(1))) void*)g,
        (__attribute__((address_space(3))) void*)l,
        16, 0, 0);
}

// ---------------------------------------------------------------------------
// Kernel 0: ic[b][o] = x_t[b,:] . W_ih[o,:] + b_ih[o]     (268 MFLOP GEMM)
// ---------------------------------------------------------------------------
__global__ __launch_bounds__(256) void input_gemm(
    const float* __restrict__ x_t,   // (B, IN)
    const float* __restrict__ W_ih,  // (H, IN)
    const float* __restrict__ b_ih,  // (H,)
    float* __restrict__ ic)          // (B, H)  [workspace]
{
    const int o0 = blockIdx.x * 64;
    const int b0 = blockIdx.y * 16;
    const int t  = threadIdx.x;

    __shared__ float Wt[64][68];   // [k][o]
    __shared__ float xs[64][17];   // [k][b]

    const int tx = t & 15;         // o group: 4 outputs at o0 + 4*tx
    const int ty = t >> 4;         // b: b0 + ty

    float acc[4] = {0.f, 0.f, 0.f, 0.f};

    for (int kc = 0; kc < IN_DIM / 64; ++kc) {
        const int k0 = kc * 64;

#pragma unroll
        for (int ii = 0; ii < 4; ++ii) {
            const int i  = t + 256 * ii;
            const int r  = i >> 4;
            const int c4 = (i & 15) * 4;
            const float4 wv = *reinterpret_cast<const float4*>(
                &W_ih[(size_t)(o0 + r) * IN_DIM + k0 + c4]);
            Wt[c4 + 0][r] = wv.x; Wt[c4 + 1][r] = wv.y;
            Wt[c4 + 2][r] = wv.z; Wt[c4 + 3][r] = wv.w;
        }
        {
            const int br = t >> 4;
            const int c4 = (t & 15) * 4;
            const float4 xv = *reinterpret_cast<const float4*>(
                &x_t[(size_t)(b0 + br) * IN_DIM + k0 + c4]);
            xs[c4 + 0][br] = xv.x; xs[c4 + 1][br] = xv.y;
            xs[c4 + 2][br] = xv.z; xs[c4 + 3][br] = xv.w;
        }
        __syncthreads();

#pragma unroll 8
        for (int k = 0; k < 64; ++k) {
            const float  xb = xs[k][ty];
            const float4 wv = *reinterpret_cast<const float4*>(&Wt[k][4 * tx]);
            acc[0] = fmaf(wv.x, xb, acc[0]);
            acc[1] = fmaf(wv.y, xb, acc[1]);
            acc[2] = fmaf(wv.z, xb, acc[2]);
            acc[3] = fmaf(wv.w, xb, acc[3]);
        }
        __syncthreads();
    }

    const int o = o0 + 4 * tx;
    const int b = b0 + ty;
    float4 r;
    r.x = acc[0] + b_ih[o + 0];
    r.y = acc[1] + b_ih[o + 1];
    r.z = acc[2] + b_ih[o + 2];
    r.w = acc[3] + b_ih[o + 3];
    *reinterpret_cast<float4*>(&ic[(size_t)b * H_DIM + o]) = r;
}

// ---------------------------------------------------------------------------
// Kernel A (v9): gumbel-softmax exchange + tanh.
//   Gumbel read path switched to global_load_lds DMA (never touches VGPRs):
//   per wave, a private 2-slot LDS ring (2 x 4 KB); 4 DMA ops per tile;
//   counted s_waitcnt vmcnt(4) (drain-free pipeline, T4); consume via
//   ds_read_b128. E rows staged in LDS with exp() fused (R8 winner).
//   grid = (B/4, H/8), block = 256 (4 waves). Wave w: b = b0+w, rows
//   o0..o0+7 (32 KB contiguous gumbel). LDS 64 KB -> 2 blocks/CU, 8 waves/CU
//   x 8 KB DMA in flight. s[8],d[8] partials; reductions deferred.
// ---------------------------------------------------------------------------
__global__ __launch_bounds__(256, 2) void fused_rows(
    const float* __restrict__ h_prev,  // (B, H)
    const float* __restrict__ W_f,     // (H, H)
    const float* __restrict__ W_v,     // (H, H)
    const float* __restrict__ gu,      // (B, H, H)
    const float* __restrict__ ic,      // (B, H)  [workspace, bias included]
    float* __restrict__ h_next)        // (B, H)  [= d_out region 0]
{
    const int b0 = blockIdx.x * 4;
    const int o0 = blockIdx.y * 8;
    const int t  = threadIdx.x;
    const int w  = t >> 6, lane = t & 63;

    __shared__ __align__(16) float e_s[8 * H_DIM];      // 32 KB exp(logits)
    __shared__ __align__(16) float ring[4][2][1024];    // 32 KB DMA ring

    // Stage exp(W_f + W_v) for rows o0..o0+7 (fused exp, no separate kernel).
    {
        const float4* f4 = reinterpret_cast<const float4*>(W_f) + (size_t)o0 * 256;
        const float4* v4 = reinterpret_cast<const float4*>(W_v) + (size_t)o0 * 256;
        float4*       dst = reinterpret_cast<float4*>(e_s);
#pragma unroll
        for (int ii = 0; ii < 8; ++ii) {
            const float4 a = f4[t + 256 * ii];
            const float4 b = v4[t + 256 * ii];
            float4 ee;
            ee.x = __expf(a.x + b.x); ee.y = __expf(a.y + b.y);
            ee.z = __expf(a.z + b.z); ee.w = __expf(a.w + b.w);
            dst[t + 256 * ii] = ee;
        }
    }
    __syncthreads();   // also drains all staging loads (compiler vmcnt(0))

    const int b = b0 + w;

    // h_prev[b] fragment -> 16 persistent VGPRs.
    const float4* hp4 = reinterpret_cast<const float4*>(h_prev + (size_t)b * H_DIM);
    float4 p[4];
#pragma unroll
    for (int j = 0; j < 4; ++j) p[j] = hp4[lane + 64 * j];

    // Drain p-loads so the DMA vmcnt counting below is exact.
    asm volatile("s_waitcnt vmcnt(0)" ::: "memory");
    __builtin_amdgcn_sched_barrier(0);

    const float* grow = gu + ((size_t)b * H_DIM + o0) * H_DIM;  // 32 KB range
    const float4* e4  = reinterpret_cast<const float4*>(e_s);

    // Prologue: DMA tiles 0 and 1 into the ring (4 ops each).
#pragma unroll
    for (int j = 0; j < 4; ++j)
        gload_lds16(grow + 0 * 1024 + j * 256 + lane * 4, &ring[w][0][j * 256]);
#pragma unroll
    for (int j = 0; j < 4; ++j)
        gload_lds16(grow + 1 * 1024 + j * 256 + lane * 4, &ring[w][1][j * 256]);

    float s[8], d[8];

#pragma unroll
    for (int oi = 0; oi < 8; ++oi) {
        const int slot = oi & 1;   // compile-time after unroll

        // Wait for tile oi's 4 DMA ops; keep tile oi+1's 4 in flight.
        if (oi < 7) {
            asm volatile("s_waitcnt vmcnt(4)" ::: "memory");
        } else {
            asm volatile("s_waitcnt vmcnt(0)" ::: "memory");
        }
        __builtin_amdgcn_sched_barrier(0);

        const float4* tile4 = reinterpret_cast<const float4*>(ring[w][slot]);

        float sum = 0.f, dot = 0.f;
#pragma unroll
        for (int j = 0; j < 4; ++j) {
            const float4 uu = tile4[lane + 64 * j];
            const float4 ee = e4[oi * 256 + lane + 64 * j];
            const float4 pp = p[j];
            const float q0 = __fdividef(ee.x, -__log2f(fmaxf(uu.x, 1e-9f)));
            const float q1 = __fdividef(ee.y, -__log2f(fmaxf(uu.y, 1e-9f)));
            const float q2 = __fdividef(ee.z, -__log2f(fmaxf(uu.z, 1e-9f)));
            const float q3 = __fdividef(ee.w, -__log2f(fmaxf(uu.w, 1e-9f)));
            sum += (q0 + q1) + (q2 + q3);
            dot = fmaf(q0, pp.x, dot);
            dot = fmaf(q1, pp.y, dot);
            dot = fmaf(q2, pp.z, dot);
            dot = fmaf(q3, pp.w, dot);
        }
        s[oi] = sum;
        d[oi] = dot;

        // Refill this slot with tile oi+2 (issued after consumption: the
        // ds_reads above have completed -- lgkmcnt waits precede the uses --
        // and DMA data lands >=100s of cycles after issue).
        if (oi < 6) {
            const float* gn = grow + (size_t)(oi + 2) * 1024;
#pragma unroll
            for (int j = 0; j < 4; ++j)
                gload_lds16(gn + j * 256 + lane * 4, &ring[w][slot][j * 256]);
        }
    }

    // 16 independent xor-reduction chains (deferred, high ILP).
#pragma unroll
    for (int off = 32; off > 0; off >>= 1) {
#pragma unroll
        for (int r = 0; r < 8; ++r) {
            s[r] += __shfl_xor(s[r], off, 64);
            d[r] += __shfl_xor(d[r], off, 64);
        }
    }

    if (lane == 0) {
        const size_t base = (size_t)b * H_DIM + o0;
        const float4 i0 = *reinterpret_cast<const float4*>(ic + base);
        const float4 i1 = *reinterpret_cast<const float4*>(ic + base + 4);
        float4 r0, r1;
        r0.x = tanhf(i0.x + __fdividef(d[0], s[0]));
        r0.y = tanhf(i0.y + __fdividef(d[1], s[1]));
        r0.z = tanhf(i0.z + __fdividef(d[2], s[2]));
        r0.w = tanhf(i0.w + __fdividef(d[3], s[3]));
        r1.x = tanhf(i1.x + __fdividef(d[4], s[4]));
        r1.y = tanhf(i1.y + __fdividef(d[5], s[5]));
        r1.z = tanhf(i1.z + __fdividef(d[6], s[6]));
        r1.w = tanhf(i1.w + __fdividef(d[7], s[7]));
        *reinterpret_cast<float4*>(h_next + base)     = r0;
        *reinterpret_cast<float4*>(h_next + base + 4) = r1;
    }
}

// ---------------------------------------------------------------------------
// Kernel B: W_out = 0.99 * W_v + (0.01/B) * (h_next^T @ h_prev)
// ---------------------------------------------------------------------------
__global__ __launch_bounds__(256) void hebbian_update(
    const float* __restrict__ h_next,  // (B, H)
    const float* __restrict__ h_prev,  // (B, H)
    const float* __restrict__ W_v,     // (H, H)
    float* __restrict__ W_out)         // (H, H)  [= d_out region 1]
{
    const int h0 = blockIdx.x * 64;
    const int o0 = blockIdx.y * 64;
    const int t  = threadIdx.x;

    __shared__ __align__(16) float hn_s[B_DIM][64];  // 32 KB
    __shared__ __align__(16) float hp_s[B_DIM][64];  // 32 KB

#pragma unroll
    for (int i = 0; i < 32; ++i) {
        const int e  = t + 256 * i;
        const int bb = e >> 6;
        const int cc = e & 63;
        hn_s[bb][cc] = h_next[(size_t)bb * H_DIM + o0 + cc];
        hp_s[bb][cc] = h_prev[(size_t)bb * H_DIM + h0 + cc];
    }
    __syncthreads();

    const int tx = t & 15;   // h group
    const int ty = t >> 4;   // o group

    float acc[4][4] = {{0.f}};

#pragma unroll 8
    for (int b = 0; b < B_DIM; ++b) {
        const float4 av = reinterpret_cast<const float4*>(hn_s[b])[ty];
        const float4 bv = reinterpret_cast<const float4*>(hp_s[b])[tx];
        const float aa[4] = {av.x, av.y, av.z, av.w};
        const float bb[4] = {bv.x, bv.y, bv.z, bv.w};
#pragma unroll
        for (int a = 0; a < 4; ++a)
#pragma unroll
            for (int c = 0; c < 4; ++c)
                acc[a][c] = fmaf(aa[a], bb[c], acc[a][c]);
    }

#pragma unroll
    for (int a = 0; a < 4; ++a) {
        const int o = o0 + 4 * ty + a;
        const size_t base = (size_t)o * H_DIM + h0 + 4 * tx;
        const float4 wv = *reinterpret_cast<const float4*>(W_v + base);
        float4 r;
        r.x = wv.x * kDecay + acc[a][0] * kLrOverB;
        r.y = wv.y * kDecay + acc[a][1] * kLrOverB;
        r.z = wv.z * kDecay + acc[a][2] * kLrOverB;
        r.w = wv.w * kDecay + acc[a][3] * kLrOverB;
        *reinterpret_cast<float4*>(W_out + base) = r;
    }
}

// ---------------------------------------------------------------------------
extern "C" void kernel_launch(void* const* d_in, const int* in_sizes, int n_in,
                              void* d_out, int out_size, void* d_ws, size_t ws_size,
                              hipStream_t stream)
{
    const float* x_t    = (const float*)d_in[0];
    const float* h_prev = (const float*)d_in[1];
    const float* W_ih   = (const float*)d_in[2];
    const float* b_ih   = (const float*)d_in[3];
    const float* W_f    = (const float*)d_in[4];
    const float* W_v    = (const float*)d_in[5];
    const float* gu     = (const float*)d_in[6];

    float* out    = (float*)d_out;
    float* h_next = out;                               // (B, H)
    float* W_out  = out + (size_t)B_DIM * H_DIM;       // (H, H)

    float* ic = (float*)d_ws;                          // (B, H) scratch

    input_gemm<<<dim3(H_DIM / 64, B_DIM / 16), 256, 0, stream>>>(
        x_t, W_ih, b_ih, ic);

    fused_rows<<<dim3(B_DIM / 4, H_DIM / 8), 256, 0, stream>>>(
        h_prev, W_f, W_v, gu, ic, h_next);

    hebbian_update<<<dim3(H_DIM / 64, H_DIM / 64), 256, 0, stream>>>(
        h_next, h_prev, W_v, W_out);
}

// Round 11
// 137.226 us; speedup vs baseline: 1.2757x; 1.2757x over previous
//
#include <hip/hip_runtime.h>
#include <hip/hip_bf16.h>
#include <cstddef>

// Problem constants (reference: B=128, IN=1024, H=1024, TAU=1.0)
#define B_DIM  128
#define IN_DIM 1024
#define H_DIM  1024

constexpr float kDecay   = 1.0f - 0.01f;    // 1 - FAST_WEIGHT_DECAY
constexpr float kLrOverB = 0.01f / 128.0f;  // FAST_WEIGHT_LR / B

// Native clang vector type: __builtin_nontemporal_load needs this.
typedef float f32x4 __attribute__((ext_vector_type(4)));

// ---------------------------------------------------------------------------
// Kernel 0: ic[b][o] = x_t[b,:] . W_ih[o,:] + b_ih[o]     (268 MFLOP GEMM)
// ---------------------------------------------------------------------------
__global__ __launch_bounds__(256) void input_gemm(
    const float* __restrict__ x_t,   // (B, IN)
    const float* __restrict__ W_ih,  // (H, IN)
    const float* __restrict__ b_ih,  // (H,)
    float* __restrict__ ic)          // (B, H)  [workspace]
{
    const int o0 = blockIdx.x * 64;
    const int b0 = blockIdx.y * 16;
    const int t  = threadIdx.x;

    __shared__ float Wt[64][68];   // [k][o]
    __shared__ float xs[64][17];   // [k][b]

    const int tx = t & 15;         // o group: 4 outputs at o0 + 4*tx
    const int ty = t >> 4;         // b: b0 + ty

    float acc[4] = {0.f, 0.f, 0.f, 0.f};

    for (int kc = 0; kc < IN_DIM / 64; ++kc) {
        const int k0 = kc * 64;

#pragma unroll
        for (int ii = 0; ii < 4; ++ii) {
            const int i  = t + 256 * ii;
            const int r  = i >> 4;
            const int c4 = (i & 15) * 4;
            const float4 wv = *reinterpret_cast<const float4*>(
                &W_ih[(size_t)(o0 + r) * IN_DIM + k0 + c4]);
            Wt[c4 + 0][r] = wv.x; Wt[c4 + 1][r] = wv.y;
            Wt[c4 + 2][r] = wv.z; Wt[c4 + 3][r] = wv.w;
        }
        {
            const int br = t >> 4;
            const int c4 = (t & 15) * 4;
            const float4 xv = *reinterpret_cast<const float4*>(
                &x_t[(size_t)(b0 + br) * IN_DIM + k0 + c4]);
            xs[c4 + 0][br] = xv.x; xs[c4 + 1][br] = xv.y;
            xs[c4 + 2][br] = xv.z; xs[c4 + 3][br] = xv.w;
        }
        __syncthreads();

#pragma unroll 8
        for (int k = 0; k < 64; ++k) {
            const float  xb = xs[k][ty];
            const float4 wv = *reinterpret_cast<const float4*>(&Wt[k][4 * tx]);
            acc[0] = fmaf(wv.x, xb, acc[0]);
            acc[1] = fmaf(wv.y, xb, acc[1]);
            acc[2] = fmaf(wv.z, xb, acc[2]);
            acc[3] = fmaf(wv.w, xb, acc[3]);
        }
        __syncthreads();
    }

    const int o = o0 + 4 * tx;
    const int b = b0 + ty;
    float4 r;
    r.x = acc[0] + b_ih[o + 0];
    r.y = acc[1] + b_ih[o + 1];
    r.z = acc[2] + b_ih[o + 2];
    r.w = acc[3] + b_ih[o + 3];
    *reinterpret_cast<float4*>(&ic[(size_t)b * H_DIM + o]) = r;
}

// ---------------------------------------------------------------------------
// Kernel A (v11): gumbel-softmax exchange + tanh. Single-round persistent.
//   grid = (H/8, B/16) = (128, 8) = 1024 blocks = exactly 4 blocks/CU,
//   ONE dispatch round. x = o-chunk: dispatch index mod 8 == o-chunk mod 8,
//   so all 8 b-chunk blocks of an o-chunk share an XCD -> weight rows hit
//   that XCD's L2 (weights ~8 MB HBM total instead of 64 MB).
//   Block: stage exp(W_f+W_v) rows o0..o0+7 in 32 KB LDS ONCE; each wave
//   then streams 4 b's x 8 rows = 128 KB of gumbel (nontemporal) through a
//   2-deep register ring with no barriers; h_prev for the next b is loaded
//   mid-batch into separate regs (compiler-tracked waits). Per b: deferred
//   16-chain shuffle reduction + lane-0 tanh epilogue.
// ---------------------------------------------------------------------------
__global__ __launch_bounds__(256, 4) void fused_rows(
    const float* __restrict__ h_prev,  // (B, H)
    const float* __restrict__ W_f,     // (H, H)
    const float* __restrict__ W_v,     // (H, H)
    const float* __restrict__ gu,      // (B, H, H)
    const float* __restrict__ ic,      // (B, H)  [workspace, bias included]
    float* __restrict__ h_next)        // (B, H)  [= d_out region 0]
{
    const int o0 = blockIdx.x * 8;
    const int b0 = blockIdx.y * 16;
    const int t  = threadIdx.x;
    const int w  = t >> 6, lane = t & 63;

    __shared__ __align__(16) float e_s[8 * H_DIM];  // 32 KB exp(logits) rows

    // Stage exp(W_f + W_v) for rows o0..o0+7 (fused exp).
    {
        const float4* f4 = reinterpret_cast<const float4*>(W_f) + (size_t)o0 * 256;
        const float4* v4 = reinterpret_cast<const float4*>(W_v) + (size_t)o0 * 256;
        float4*       dst = reinterpret_cast<float4*>(e_s);
#pragma unroll
        for (int ii = 0; ii < 8; ++ii) {
            const float4 a = f4[t + 256 * ii];
            const float4 b = v4[t + 256 * ii];
            float4 ee;
            ee.x = __expf(a.x + b.x); ee.y = __expf(a.y + b.y);
            ee.z = __expf(a.z + b.z); ee.w = __expf(a.w + b.w);
            dst[t + 256 * ii] = ee;
        }
    }
    __syncthreads();

    const float4* e4 = reinterpret_cast<const float4*>(e_s);
    const int bA = b0 + w;   // wave's first b; sequence: bA + 4k, k = 0..3

    // h_prev[bA] fragment -> 16 persistent VGPRs.
    float4 pc[4], pn[4];
    {
        const float4* hp4 = reinterpret_cast<const float4*>(h_prev + (size_t)bA * H_DIM);
#pragma unroll
        for (int j = 0; j < 4; ++j) pc[j] = hp4[lane + 64 * j];
    }

    f32x4 ug[2][4];   // 2-deep register ring (8 KB in flight per wave)

    // Prologue: tiles 0,1 of k=0 (nontemporal one-touch stream).
    {
        const f32x4* g0 = reinterpret_cast<const f32x4*>(gu)
                        + ((size_t)bA * H_DIM + o0) * 256;
#pragma unroll
        for (int j = 0; j < 4; ++j)
            ug[0][j] = __builtin_nontemporal_load(g0 + lane + 64 * j);
#pragma unroll
        for (int j = 0; j < 4; ++j)
            ug[1][j] = __builtin_nontemporal_load(g0 + 256 + lane + 64 * j);
    }

#pragma unroll
    for (int k = 0; k < 4; ++k) {
        const int b = bA + 4 * k;
        const f32x4* gk  = reinterpret_cast<const f32x4*>(gu)
                         + ((size_t)b * H_DIM + o0) * 256;
        const f32x4* gk1 = reinterpret_cast<const f32x4*>(gu)
                         + ((size_t)(b + 4) * H_DIM + o0) * 256;  // next b

        float s[8], d[8];

#pragma unroll
        for (int oi = 0; oi < 8; ++oi) {
            const int slot = oi & 1;   // compile-time after unroll

            float sum = 0.f, dot = 0.f;
#pragma unroll
            for (int j = 0; j < 4; ++j) {
                const f32x4  uu = ug[slot][j];
                const float4 ee = e4[oi * 256 + lane + 64 * j];
                const float4 pp = pc[j];
                const float q0 = __fdividef(ee.x, -__log2f(fmaxf(uu.x, 1e-9f)));
                const float q1 = __fdividef(ee.y, -__log2f(fmaxf(uu.y, 1e-9f)));
                const float q2 = __fdividef(ee.z, -__log2f(fmaxf(uu.z, 1e-9f)));
                const float q3 = __fdividef(ee.w, -__log2f(fmaxf(uu.w, 1e-9f)));
                sum += (q0 + q1) + (q2 + q3);
                dot = fmaf(q0, pp.x, dot);
                dot = fmaf(q1, pp.y, dot);
                dot = fmaf(q2, pp.z, dot);
                dot = fmaf(q3, pp.w, dot);
            }
            s[oi] = sum;
            d[oi] = dot;

            // Refill this slot with global tile +2 (crosses into next b).
            if (k < 3 || oi < 6) {
                const f32x4* gsrc = (oi < 6) ? (gk + (size_t)(oi + 2) * 256)
                                             : (gk1 + (size_t)(oi - 6) * 256);
#pragma unroll
                for (int j = 0; j < 4; ++j)
                    ug[slot][j] = __builtin_nontemporal_load(gsrc + lane + 64 * j);
            }

            // Mid-batch: issue next b's h_prev loads (L2-hit, compiler-tracked).
            if (oi == 3 && k < 3) {
                const float4* hpn = reinterpret_cast<const float4*>(
                    h_prev + (size_t)(b + 4) * H_DIM);
#pragma unroll
                for (int j = 0; j < 4; ++j) pn[j] = hpn[lane + 64 * j];
            }
        }

        // 16 independent xor-reduction chains for this b (deferred, high ILP).
#pragma unroll
        for (int off = 32; off > 0; off >>= 1) {
#pragma unroll
            for (int r = 0; r < 8; ++r) {
                s[r] += __shfl_xor(s[r], off, 64);
                d[r] += __shfl_xor(d[r], off, 64);
            }
        }

        if (lane == 0) {
            const size_t base = (size_t)b * H_DIM + o0;
            const float4 i0 = *reinterpret_cast<const float4*>(ic + base);
            const float4 i1 = *reinterpret_cast<const float4*>(ic + base + 4);
            float4 r0, r1;
            r0.x = tanhf(i0.x + __fdividef(d[0], s[0]));
            r0.y = tanhf(i0.y + __fdividef(d[1], s[1]));
            r0.z = tanhf(i0.z + __fdividef(d[2], s[2]));
            r0.w = tanhf(i0.w + __fdividef(d[3], s[3]));
            r1.x = tanhf(i1.x + __fdividef(d[4], s[4]));
            r1.y = tanhf(i1.y + __fdividef(d[5], s[5]));
            r1.z = tanhf(i1.z + __fdividef(d[6], s[6]));
            r1.w = tanhf(i1.w + __fdividef(d[7], s[7]));
            *reinterpret_cast<float4*>(h_next + base)     = r0;
            *reinterpret_cast<float4*>(h_next + base + 4) = r1;
        }

        // Rotate h_prev fragment for next b (static, register rename).
        if (k < 3) {
#pragma unroll
            for (int j = 0; j < 4; ++j) pc[j] = pn[j];
        }
    }
}

// ---------------------------------------------------------------------------
// Kernel B: W_out = 0.99 * W_v + (0.01/B) * (h_next^T @ h_prev)
// ---------------------------------------------------------------------------
__global__ __launch_bounds__(256) void hebbian_update(
    const float* __restrict__ h_next,  // (B, H)
    const float* __restrict__ h_prev,  // (B, H)
    const float* __restrict__ W_v,     // (H, H)
    float* __restrict__ W_out)         // (H, H)  [= d_out region 1]
{
    const int h0 = blockIdx.x * 64;
    const int o0 = blockIdx.y * 64;
    const int t  = threadIdx.x;

    __shared__ __align__(16) float hn_s[B_DIM][64];  // 32 KB
    __shared__ __align__(16) float hp_s[B_DIM][64];  // 32 KB

#pragma unroll
    for (int i = 0; i < 32; ++i) {
        const int e  = t + 256 * i;
        const int bb = e >> 6;
        const int cc = e & 63;
        hn_s[bb][cc] = h_next[(size_t)bb * H_DIM + o0 + cc];
        hp_s[bb][cc] = h_prev[(size_t)bb * H_DIM + h0 + cc];
    }
    __syncthreads();

    const int tx = t & 15;   // h group
    const int ty = t >> 4;   // o group

    float acc[4][4] = {{0.f}};

#pragma unroll 8
    for (int b = 0; b < B_DIM; ++b) {
        const float4 av = reinterpret_cast<const float4*>(hn_s[b])[ty];
        const float4 bv = reinterpret_cast<const float4*>(hp_s[b])[tx];
        const float aa[4] = {av.x, av.y, av.z, av.w};
        const float bb[4] = {bv.x, bv.y, bv.z, bv.w};
#pragma unroll
        for (int a = 0; a < 4; ++a)
#pragma unroll
            for (int c = 0; c < 4; ++c)
                acc[a][c] = fmaf(aa[a], bb[c], acc[a][c]);
    }

#pragma unroll
    for (int a = 0; a < 4; ++a) {
        const int o = o0 + 4 * ty + a;
        const size_t base = (size_t)o * H_DIM + h0 + 4 * tx;
        const float4 wv = *reinterpret_cast<const float4*>(W_v + base);
        float4 r;
        r.x = wv.x * kDecay + acc[a][0] * kLrOverB;
        r.y = wv.y * kDecay + acc[a][1] * kLrOverB;
        r.z = wv.z * kDecay + acc[a][2] * kLrOverB;
        r.w = wv.w * kDecay + acc[a][3] * kLrOverB;
        *reinterpret_cast<float4*>(W_out + base) = r;
    }
}

// ---------------------------------------------------------------------------
extern "C" void kernel_launch(void* const* d_in, const int* in_sizes, int n_in,
                              void* d_out, int out_size, void* d_ws, size_t ws_size,
                              hipStream_t stream)
{
    const float* x_t    = (const float*)d_in[0];
    const float* h_prev = (const float*)d_in[1];
    const float* W_ih   = (const float*)d_in[2];
    const float* b_ih   = (const float*)d_in[3];
    const float* W_f    = (const float*)d_in[4];
    const float* W_v    = (const float*)d_in[5];
    const float* gu     = (const float*)d_in[6];

    float* out    = (float*)d_out;
    float* h_next = out;                               // (B, H)
    float* W_out  = out + (size_t)B_DIM * H_DIM;       // (H, H)

    float* ic = (float*)d_ws;                          // (B, H) scratch

    input_gemm<<<dim3(H_DIM / 64, B_DIM / 16), 256, 0, stream>>>(
        x_t, W_ih, b_ih, ic);

    fused_rows<<<dim3(H_DIM / 8, B_DIM / 16), 256, 0, stream>>>(
        h_prev, W_f, W_v, gu, ic, h_next);

    hebbian_update<<<dim3(H_DIM / 64, H_DIM / 64), 256, 0, stream>>>(
        h_next, h_prev, W_v, W_out);
}